// Round 1
// baseline (1135.322 us; speedup 1.0000x reference)
//
#include <hip/hip_runtime.h>
#include <stdint.h>

#define BB 4
#define LL 16384
#define CC 512
#define MM (BB * LL)  // 65536

typedef unsigned short u16;
typedef __bf16 bf16x8 __attribute__((ext_vector_type(8)));
typedef float f32x4 __attribute__((ext_vector_type(4)));
typedef u16 u16x8 __attribute__((ext_vector_type(8)));
typedef u16 u16x4 __attribute__((ext_vector_type(4)));

__device__ __forceinline__ u16 f2bf(float f) {
  union { float f; uint32_t u; } c; c.f = f;
  return (u16)((c.u + 0x7fffu + ((c.u >> 16) & 1u)) >> 16);
}

__device__ __forceinline__ void gl_lds16(const void* g, void* l) {
  __builtin_amdgcn_global_load_lds((const __attribute__((address_space(1))) void*)g,
                                   (__attribute__((address_space(3))) void*)l,
                                   16, 0, 0);
}

// ---------------- fp32 -> bf16 convert (vectorized) ----------------
__global__ void cvt_kernel(const float* __restrict__ in, u16* __restrict__ out, int n4) {
  for (int i = blockIdx.x * blockDim.x + threadIdx.x; i < n4; i += gridDim.x * blockDim.x) {
    float4 v = reinterpret_cast<const float4*>(in)[i];
    u16x4 o;
    o[0] = f2bf(v.x); o[1] = f2bf(v.y); o[2] = f2bf(v.z); o[3] = f2bf(v.w);
    reinterpret_cast<u16x4*>(out)[i] = o;
  }
}

// ---------------- weight transpose + convert: W[K][N] -> Wt[N][K] bf16 ----------------
__global__ void tcvt_kernel(const float* __restrict__ W, u16* __restrict__ Wt, int K, int N) {
  int idx = blockIdx.x * blockDim.x + threadIdx.x;
  if (idx >= K * N) return;
  int n = idx / K, k = idx % K;
  Wt[idx] = f2bf(W[k * N + n]);
}

// ---------------- NT GEMM: C[M][N] = A[M][K] * Bt[N][K]^T, bf16 in, bf16/f32 out ----
template <bool OUT_F32>
__global__ __launch_bounds__(256) void gemm_nt(const u16* __restrict__ A,
                                               const u16* __restrict__ Bt,
                                               void* __restrict__ Cp,
                                               int M, int N, int K) {
  __shared__ __align__(16) u16 Al[2][128 * 32];
  __shared__ __align__(16) u16 Bl[2][128 * 32];
  const int nbn = N >> 7;
  const int bm = blockIdx.x / nbn, bn = blockIdx.x % nbn;
  const int row0 = bm << 7, col0 = bn << 7;
  const int tid = threadIdx.x;
  const int lane = tid & 63;
  const int wv = tid >> 6, wr = wv >> 1, wc = wv & 1;
  f32x4 acc[4][4] = {};
  const int nkt = K >> 5;

  auto stage = [&](int buf, int kt) {
#pragma unroll
    for (int i = 0; i < 2; ++i) {
      int ci = i * 256 + tid;           // 0..511 chunks of 16B
      int r = ci >> 2, c = (ci & 3) << 3;
      gl_lds16(A + (size_t)(row0 + r) * K + kt * 32 + c, &Al[buf][ci * 8]);
      gl_lds16(Bt + (size_t)(col0 + r) * K + kt * 32 + c, &Bl[buf][ci * 8]);
    }
  };

  stage(0, 0);
  __syncthreads();
  for (int kt = 0; kt < nkt; ++kt) {
    int cur = kt & 1;
    if (kt + 1 < nkt) stage(cur ^ 1, kt + 1);
    bf16x8 af[4], bfv[4];
    const int ro = lane & 15, ko = (lane >> 4) << 3;
#pragma unroll
    for (int m = 0; m < 4; ++m)
      af[m] = *reinterpret_cast<const bf16x8*>(&Al[cur][(64 * wr + 16 * m + ro) * 32 + ko]);
#pragma unroll
    for (int n = 0; n < 4; ++n)
      bfv[n] = *reinterpret_cast<const bf16x8*>(&Bl[cur][(64 * wc + 16 * n + ro) * 32 + ko]);
#pragma unroll
    for (int m = 0; m < 4; ++m)
#pragma unroll
      for (int n = 0; n < 4; ++n)
        acc[m][n] = __builtin_amdgcn_mfma_f32_16x16x32_bf16(af[m], bfv[n], acc[m][n], 0, 0, 0);
    __syncthreads();
  }

#pragma unroll
  for (int m = 0; m < 4; ++m)
#pragma unroll
    for (int n = 0; n < 4; ++n)
#pragma unroll
      for (int j = 0; j < 4; ++j) {
        int r = row0 + 64 * wr + 16 * m + (lane >> 4) * 4 + j;
        int c = col0 + 64 * wc + 16 * n + (lane & 15);
        if (OUT_F32)
          reinterpret_cast<float*>(Cp)[(size_t)r * N + c] = acc[m][n][j];
        else
          reinterpret_cast<u16*>(Cp)[(size_t)r * N + c] = f2bf(acc[m][n][j]);
      }
}

// ---------------- window attention ----------------
// grid: b*512 + w*8 + h  (2048 blocks), 512 threads (8 waves, 32 q-rows each)
__global__ __launch_bounds__(512, 2) void attn_kernel(const u16* __restrict__ qp,
                                                      const u16* __restrict__ kvp,
                                                      u16* __restrict__ o) {
  __shared__ __align__(16) u16 Kl[256 * 72];       // K tile, padded rows
  __shared__ __align__(16) u16 Vt[64 * 264];       // V transposed, padded rows
  __shared__ __align__(16) u16 Pl[8 * 16 * 264];   // per-wave P row-tile
  const int bid = blockIdx.x;
  const int h = bid & 7, w = (bid >> 3) & 63, b = bid >> 9;
  const int w1 = w >> 3, w2 = w & 7;
  const int tid = threadIdx.x, lane = tid & 63, wv = tid >> 6;

  auto lrow = [&](int t) { return (w1 * 16 + (t >> 4)) * 128 + w2 * 16 + (t & 15); };

  {  // stage K rows and V transposed
    const int t = tid >> 1, half = tid & 1;
    const size_t base = ((size_t)(b * LL + lrow(t))) * 1024 + h * 64 + half * 32;
    const u16* kr = kvp + base;
    const u16* vr = kvp + base + 512;
#pragma unroll
    for (int c = 0; c < 4; ++c) {
      u16x8 kx = *reinterpret_cast<const u16x8*>(kr + c * 8);
      *reinterpret_cast<u16x8*>(&Kl[t * 72 + half * 32 + c * 8]) = kx;
    }
#pragma unroll
    for (int c = 0; c < 4; ++c) {
      u16x8 vx = *reinterpret_cast<const u16x8*>(vr + c * 8);
#pragma unroll
      for (int e = 0; e < 8; ++e) Vt[(half * 32 + c * 8 + e) * 264 + t] = vx[e];
    }
  }

  // Q fragments direct from global
  bf16x8 qf[2][2];
  {
    const int tq = 32 * wv + (lane & 15);
#pragma unroll
    for (int rt = 0; rt < 2; ++rt) {
      const size_t qbase =
          ((size_t)(b * LL + lrow(tq + 16 * rt))) * 512 + h * 64 + ((lane >> 4) << 3);
      qf[rt][0] = *reinterpret_cast<const bf16x8*>(qp + qbase);
      qf[rt][1] = *reinterpret_cast<const bf16x8*>(qp + qbase + 32);
    }
  }
  __syncthreads();

  // S = Q K^T  (per wave: 32 q-rows x 256 keys)
  f32x4 sa[2][16] = {};
  {
    const int ro = lane & 15, ko = (lane >> 4) << 3;
#pragma unroll
    for (int ct = 0; ct < 16; ++ct) {
      bf16x8 kf0 = *reinterpret_cast<const bf16x8*>(&Kl[(16 * ct + ro) * 72 + ko]);
      bf16x8 kf1 = *reinterpret_cast<const bf16x8*>(&Kl[(16 * ct + ro) * 72 + 32 + ko]);
#pragma unroll
      for (int rt = 0; rt < 2; ++rt) {
        sa[rt][ct] = __builtin_amdgcn_mfma_f32_16x16x32_bf16(qf[rt][0], kf0, sa[rt][ct], 0, 0, 0);
        sa[rt][ct] = __builtin_amdgcn_mfma_f32_16x16x32_bf16(qf[rt][1], kf1, sa[rt][ct], 0, 0, 0);
      }
    }
  }

  const float scale = 0.125f;  // hd^-0.5, hd=64
  f32x4 oacc[2][4] = {};
  const int pbase = wv * 16 * 264;
  for (int rt = 0; rt < 2; ++rt) {
#pragma unroll
    for (int j = 0; j < 4; ++j) {
      float m = -1e30f;
#pragma unroll
      for (int ct = 0; ct < 16; ++ct) m = fmaxf(m, sa[rt][ct][j]);
      m = fmaxf(m, __shfl_xor(m, 1));
      m = fmaxf(m, __shfl_xor(m, 2));
      m = fmaxf(m, __shfl_xor(m, 4));
      m = fmaxf(m, __shfl_xor(m, 8));
      m *= scale;
      float s = 0.f;
#pragma unroll
      for (int ct = 0; ct < 16; ++ct) {
        float p = __expf(sa[rt][ct][j] * scale - m);
        sa[rt][ct][j] = p;
        s += p;
      }
      s += __shfl_xor(s, 1);
      s += __shfl_xor(s, 2);
      s += __shfl_xor(s, 4);
      s += __shfl_xor(s, 8);
      float inv = 1.f / s;
#pragma unroll
      for (int ct = 0; ct < 16; ++ct)
        Pl[pbase + ((lane >> 4) * 4 + j) * 264 + 16 * ct + (lane & 15)] =
            f2bf(sa[rt][ct][j] * inv);
    }
    __syncthreads();
    // O += P V
#pragma unroll
    for (int ks = 0; ks < 8; ++ks) {
      bf16x8 pf = *reinterpret_cast<const bf16x8*>(
          &Pl[pbase + (lane & 15) * 264 + ks * 32 + ((lane >> 4) << 3)]);
#pragma unroll
      for (int cd = 0; cd < 4; ++cd) {
        bf16x8 vf = *reinterpret_cast<const bf16x8*>(
            &Vt[(16 * cd + (lane & 15)) * 264 + ks * 32 + ((lane >> 4) << 3)]);
        oacc[rt][cd] = __builtin_amdgcn_mfma_f32_16x16x32_bf16(pf, vf, oacc[rt][cd], 0, 0, 0);
      }
    }
  }

#pragma unroll
  for (int rt = 0; rt < 2; ++rt)
#pragma unroll
    for (int cd = 0; cd < 4; ++cd)
#pragma unroll
      for (int j = 0; j < 4; ++j) {
        int t = 32 * wv + 16 * rt + (lane >> 4) * 4 + j;
        int d = 16 * cd + (lane & 15);
        o[((size_t)(b * LL + lrow(t))) * 512 + h * 64 + d] = f2bf(oacc[rt][cd][j]);
      }
}

// ---------------- launch ----------------
extern "C" void kernel_launch(void* const* d_in, const int* in_sizes, int n_in,
                              void* d_out, int out_size, void* d_ws, size_t ws_size,
                              hipStream_t stream) {
  const float* q = (const float*)d_in[0];
  const float* kv = (const float*)d_in[1];
  const float* Wq = (const float*)d_in[2];
  const float* Wkv = (const float*)d_in[3];
  const float* Wfc = (const float*)d_in[4];
  float* out = (float*)d_out;
  char* ws = (char*)d_ws;

  // workspace layout (bytes)
  u16* q_bf  = (u16*)(ws + 0);            // 67108864  (also reused as o_buf)
  u16* kv_bf = (u16*)(ws + 67108864);     // 67108864
  u16* qp    = (u16*)(ws + 134217728);    // 67108864
  u16* kvp   = (u16*)(ws + 201326592);    // 134217728
  u16* Wq_t  = (u16*)(ws + 335544320);    // 524288
  u16* Wkv_t = (u16*)(ws + 336068608);    // 1048576
  u16* Wfc_t = (u16*)(ws + 337117184);    // 524288
  u16* o_buf = q_bf;                      // q_bf dead after GEMM1

  const int n4 = MM * CC / 4;  // 8388608
  cvt_kernel<<<2048, 256, 0, stream>>>(q, q_bf, n4);
  cvt_kernel<<<2048, 256, 0, stream>>>(kv, kv_bf, n4);
  tcvt_kernel<<<(CC * CC + 255) / 256, 256, 0, stream>>>(Wq, Wq_t, CC, CC);
  tcvt_kernel<<<(CC * 2 * CC + 255) / 256, 256, 0, stream>>>(Wkv, Wkv_t, CC, 2 * CC);
  tcvt_kernel<<<(CC * CC + 255) / 256, 256, 0, stream>>>(Wfc, Wfc_t, CC, CC);

  gemm_nt<false><<<(MM / 128) * (CC / 128), 256, 0, stream>>>(q_bf, Wq_t, qp, MM, CC, CC);
  gemm_nt<false><<<(MM / 128) * (2 * CC / 128), 256, 0, stream>>>(kv_bf, Wkv_t, kvp, MM, 2 * CC, CC);

  attn_kernel<<<BB * 64 * 8, 512, 0, stream>>>(qp, kvp, o_buf);

  gemm_nt<true><<<(MM / 128) * (CC / 128), 256, 0, stream>>>(o_buf, Wfc_t, out, MM, CC, CC);
}

// Round 2
// 449.709 us; speedup vs baseline: 2.5246x; 2.5246x over previous
//
#include <hip/hip_runtime.h>
#include <stdint.h>

#define BB 4
#define LL 16384
#define CC 512
#define MM (BB * LL)  // 65536

typedef unsigned short u16;
typedef __bf16 bf16x8 __attribute__((ext_vector_type(8)));
typedef float f32x4 __attribute__((ext_vector_type(4)));
typedef u16 u16x8 __attribute__((ext_vector_type(8)));
typedef u16 u16x4 __attribute__((ext_vector_type(4)));

__device__ __forceinline__ u16 f2bf(float f) {
  union { float f; uint32_t u; } c; c.f = f;
  return (u16)((c.u + 0x7fffu + ((c.u >> 16) & 1u)) >> 16);
}

__device__ __forceinline__ void gl_lds16(const void* g, void* l) {
  __builtin_amdgcn_global_load_lds((const __attribute__((address_space(1))) void*)g,
                                   (__attribute__((address_space(3))) void*)l,
                                   16, 0, 0);
}

// ---------------- fp32 -> bf16 convert (vectorized) ----------------
__global__ void cvt_kernel(const float* __restrict__ in, u16* __restrict__ out, int n4) {
  for (int i = blockIdx.x * blockDim.x + threadIdx.x; i < n4; i += gridDim.x * blockDim.x) {
    float4 v = reinterpret_cast<const float4*>(in)[i];
    u16x4 o;
    o[0] = f2bf(v.x); o[1] = f2bf(v.y); o[2] = f2bf(v.z); o[3] = f2bf(v.w);
    reinterpret_cast<u16x4*>(out)[i] = o;
  }
}

// ---------------- weight transpose + convert: W[K][N] -> Wt[N][K] bf16 ----------------
__global__ void tcvt_kernel(const float* __restrict__ W, u16* __restrict__ Wt, int K, int N) {
  int idx = blockIdx.x * blockDim.x + threadIdx.x;
  if (idx >= K * N) return;
  int n = idx / K, k = idx % K;
  Wt[idx] = f2bf(W[k * N + n]);
}

// ---------------- NT GEMM: C[M][N] = A[M][K] * Bt[N][K]^T, bf16 in, bf16/f32 out ----
template <bool OUT_F32>
__global__ __launch_bounds__(256) void gemm_nt(const u16* __restrict__ A,
                                               const u16* __restrict__ Bt,
                                               void* __restrict__ Cp,
                                               int M, int N, int K) {
  __shared__ __align__(16) u16 Al[2][128 * 32];
  __shared__ __align__(16) u16 Bl[2][128 * 32];
  const int nbn = N >> 7;
  const int bm = blockIdx.x / nbn, bn = blockIdx.x % nbn;
  const int row0 = bm << 7, col0 = bn << 7;
  const int tid = threadIdx.x;
  const int lane = tid & 63;
  const int wv = tid >> 6, wr = wv >> 1, wc = wv & 1;
  f32x4 acc[4][4] = {};
  const int nkt = K >> 5;

  auto stage = [&](int buf, int kt) {
#pragma unroll
    for (int i = 0; i < 2; ++i) {
      int ci = i * 256 + tid;           // 0..511 chunks of 16B
      int r = ci >> 2, c = (ci & 3) << 3;
      gl_lds16(A + (size_t)(row0 + r) * K + kt * 32 + c, &Al[buf][ci * 8]);
      gl_lds16(Bt + (size_t)(col0 + r) * K + kt * 32 + c, &Bl[buf][ci * 8]);
    }
  };

  stage(0, 0);
  __syncthreads();
  for (int kt = 0; kt < nkt; ++kt) {
    int cur = kt & 1;
    if (kt + 1 < nkt) stage(cur ^ 1, kt + 1);
    bf16x8 af[4], bfv[4];
    const int ro = lane & 15, ko = (lane >> 4) << 3;
#pragma unroll
    for (int m = 0; m < 4; ++m)
      af[m] = *reinterpret_cast<const bf16x8*>(&Al[cur][(64 * wr + 16 * m + ro) * 32 + ko]);
#pragma unroll
    for (int n = 0; n < 4; ++n)
      bfv[n] = *reinterpret_cast<const bf16x8*>(&Bl[cur][(64 * wc + 16 * n + ro) * 32 + ko]);
#pragma unroll
    for (int m = 0; m < 4; ++m)
#pragma unroll
      for (int n = 0; n < 4; ++n)
        acc[m][n] = __builtin_amdgcn_mfma_f32_16x16x32_bf16(af[m], bfv[n], acc[m][n], 0, 0, 0);
    __syncthreads();
  }

#pragma unroll
  for (int m = 0; m < 4; ++m)
#pragma unroll
    for (int n = 0; n < 4; ++n)
#pragma unroll
      for (int j = 0; j < 4; ++j) {
        int r = row0 + 64 * wr + 16 * m + (lane >> 4) * 4 + j;
        int c = col0 + 64 * wc + 16 * n + (lane & 15);
        if (OUT_F32)
          reinterpret_cast<float*>(Cp)[(size_t)r * N + c] = acc[m][n][j];
        else
          reinterpret_cast<u16*>(Cp)[(size_t)r * N + c] = f2bf(acc[m][n][j]);
      }
}

// ---------------- window attention ----------------
// grid: b*512 + w*8 + h  (2048 blocks), 512 threads (8 waves, 32 q-rows each)
// Two 16-row q-tiles per wave processed SEQUENTIALLY (static indexing, no spill).
__global__ __launch_bounds__(512, 2) void attn_kernel(const u16* __restrict__ qp,
                                                      const u16* __restrict__ kvp,
                                                      u16* __restrict__ o) {
  __shared__ __align__(16) u16 Kl[256 * 72];       // K tile, padded rows
  __shared__ __align__(16) u16 Vt[64 * 264];       // V transposed, padded rows
  __shared__ __align__(16) u16 Pl[8 * 16 * 264];   // per-wave P row-tile
  const int bid = blockIdx.x;
  const int h = bid & 7, w = (bid >> 3) & 63, b = bid >> 9;
  const int w1 = w >> 3, w2 = w & 7;
  const int tid = threadIdx.x, lane = tid & 63, wv = tid >> 6;

  auto lrow = [&](int t) { return (w1 * 16 + (t >> 4)) * 128 + w2 * 16 + (t & 15); };

  {  // stage K rows and V transposed
    const int t = tid >> 1, half = tid & 1;
    const size_t base = ((size_t)(b * LL + lrow(t))) * 1024 + h * 64 + half * 32;
    const u16* kr = kvp + base;
    const u16* vr = kvp + base + 512;
#pragma unroll
    for (int c = 0; c < 4; ++c) {
      u16x8 kx = *reinterpret_cast<const u16x8*>(kr + c * 8);
      *reinterpret_cast<u16x8*>(&Kl[t * 72 + half * 32 + c * 8]) = kx;
    }
#pragma unroll
    for (int c = 0; c < 4; ++c) {
      u16x8 vx = *reinterpret_cast<const u16x8*>(vr + c * 8);
#pragma unroll
      for (int e = 0; e < 8; ++e) Vt[(half * 32 + c * 8 + e) * 264 + t] = vx[e];
    }
  }
  __syncthreads();

  const int ro = lane & 15;       // low nibble
  const int g4 = lane >> 4;       // lane group 0..3
  const float scale = 0.125f;     // hd^-0.5, hd=64
  const int pbase = wv * 16 * 264;

#pragma unroll
  for (int rt = 0; rt < 2; ++rt) {
    // Q fragments for this 16-row tile, direct from global
    const int tq = 32 * wv + 16 * rt + ro;
    const size_t qbase = ((size_t)(b * LL + lrow(tq))) * 512 + h * 64 + g4 * 8;
    const bf16x8 qf0 = *reinterpret_cast<const bf16x8*>(qp + qbase);
    const bf16x8 qf1 = *reinterpret_cast<const bf16x8*>(qp + qbase + 32);

    // S = Q K^T : 16 q-rows x 256 keys
    f32x4 sa[16] = {};
#pragma unroll
    for (int ct = 0; ct < 16; ++ct) {
      bf16x8 kf0 = *reinterpret_cast<const bf16x8*>(&Kl[(16 * ct + ro) * 72 + g4 * 8]);
      bf16x8 kf1 = *reinterpret_cast<const bf16x8*>(&Kl[(16 * ct + ro) * 72 + 32 + g4 * 8]);
      sa[ct] = __builtin_amdgcn_mfma_f32_16x16x32_bf16(qf0, kf0, sa[ct], 0, 0, 0);
      sa[ct] = __builtin_amdgcn_mfma_f32_16x16x32_bf16(qf1, kf1, sa[ct], 0, 0, 0);
    }

    // softmax per q-row (row = g4*4 + j, key = 16*ct + ro)
#pragma unroll
    for (int j = 0; j < 4; ++j) {
      float m = -1e30f;
#pragma unroll
      for (int ct = 0; ct < 16; ++ct) m = fmaxf(m, sa[ct][j]);
      m = fmaxf(m, __shfl_xor(m, 1));
      m = fmaxf(m, __shfl_xor(m, 2));
      m = fmaxf(m, __shfl_xor(m, 4));
      m = fmaxf(m, __shfl_xor(m, 8));
      m *= scale;
      float s = 0.f;
#pragma unroll
      for (int ct = 0; ct < 16; ++ct) {
        float p = __expf(sa[ct][j] * scale - m);
        sa[ct][j] = p;
        s += p;
      }
      s += __shfl_xor(s, 1);
      s += __shfl_xor(s, 2);
      s += __shfl_xor(s, 4);
      s += __shfl_xor(s, 8);
      float inv = 1.f / s;
#pragma unroll
      for (int ct = 0; ct < 16; ++ct)
        Pl[pbase + (g4 * 4 + j) * 264 + 16 * ct + ro] = f2bf(sa[ct][j] * inv);
    }

    // O = P V  (per-wave LDS region; in-wave DS ordering suffices, no barrier)
    f32x4 oacc[4] = {};
#pragma unroll
    for (int ks = 0; ks < 8; ++ks) {
      bf16x8 pf = *reinterpret_cast<const bf16x8*>(&Pl[pbase + ro * 264 + ks * 32 + g4 * 8]);
#pragma unroll
      for (int cd = 0; cd < 4; ++cd) {
        bf16x8 vf = *reinterpret_cast<const bf16x8*>(&Vt[(16 * cd + ro) * 264 + ks * 32 + g4 * 8]);
        oacc[cd] = __builtin_amdgcn_mfma_f32_16x16x32_bf16(pf, vf, oacc[cd], 0, 0, 0);
      }
    }

    // write out this 16-row tile
#pragma unroll
    for (int cd = 0; cd < 4; ++cd)
#pragma unroll
      for (int j = 0; j < 4; ++j) {
        int t = 32 * wv + 16 * rt + g4 * 4 + j;
        int d = 16 * cd + ro;
        o[((size_t)(b * LL + lrow(t))) * 512 + h * 64 + d] = f2bf(oacc[cd][j]);
      }
  }
}

// ---------------- launch ----------------
extern "C" void kernel_launch(void* const* d_in, const int* in_sizes, int n_in,
                              void* d_out, int out_size, void* d_ws, size_t ws_size,
                              hipStream_t stream) {
  const float* q = (const float*)d_in[0];
  const float* kv = (const float*)d_in[1];
  const float* Wq = (const float*)d_in[2];
  const float* Wkv = (const float*)d_in[3];
  const float* Wfc = (const float*)d_in[4];
  float* out = (float*)d_out;
  char* ws = (char*)d_ws;

  // workspace layout (bytes)
  u16* q_bf  = (u16*)(ws + 0);            // 67108864  (also reused as o_buf)
  u16* kv_bf = (u16*)(ws + 67108864);     // 67108864
  u16* qp    = (u16*)(ws + 134217728);    // 67108864
  u16* kvp   = (u16*)(ws + 201326592);    // 134217728
  u16* Wq_t  = (u16*)(ws + 335544320);    // 524288
  u16* Wkv_t = (u16*)(ws + 336068608);    // 1048576
  u16* Wfc_t = (u16*)(ws + 337117184);    // 524288
  u16* o_buf = q_bf;                      // q_bf dead after GEMM1

  const int n4 = MM * CC / 4;  // 8388608
  cvt_kernel<<<2048, 256, 0, stream>>>(q, q_bf, n4);
  cvt_kernel<<<2048, 256, 0, stream>>>(kv, kv_bf, n4);
  tcvt_kernel<<<(CC * CC + 255) / 256, 256, 0, stream>>>(Wq, Wq_t, CC, CC);
  tcvt_kernel<<<(CC * 2 * CC + 255) / 256, 256, 0, stream>>>(Wkv, Wkv_t, CC, 2 * CC);
  tcvt_kernel<<<(CC * CC + 255) / 256, 256, 0, stream>>>(Wfc, Wfc_t, CC, CC);

  gemm_nt<false><<<(MM / 128) * (CC / 128), 256, 0, stream>>>(q_bf, Wq_t, qp, MM, CC, CC);
  gemm_nt<false><<<(MM / 128) * (2 * CC / 128), 256, 0, stream>>>(kv_bf, Wkv_t, kvp, MM, 2 * CC, CC);

  attn_kernel<<<BB * 64 * 8, 512, 0, stream>>>(qp, kvp, o_buf);

  gemm_nt<true><<<(MM / 128) * (CC / 128), 256, 0, stream>>>(o_buf, Wfc_t, out, MM, CC, CC);
}

// Round 4
// 404.761 us; speedup vs baseline: 2.8049x; 1.1111x over previous
//
#include <hip/hip_runtime.h>
#include <stdint.h>

#define BB 4
#define LL 16384
#define CC 512
#define MM (BB * LL)  // 65536

typedef unsigned short u16;
typedef __bf16 bf16x8 __attribute__((ext_vector_type(8)));
typedef float f32x4 __attribute__((ext_vector_type(4)));
typedef u16 u16x8 __attribute__((ext_vector_type(8)));
typedef u16 u16x4 __attribute__((ext_vector_type(4)));

__device__ __forceinline__ u16 f2bf(float f) {
  union { float f; uint32_t u; } c; c.f = f;
  return (u16)((c.u + 0x7fffu + ((c.u >> 16) & 1u)) >> 16);
}

__device__ __forceinline__ void gl_lds16(const void* g, void* l) {
  __builtin_amdgcn_global_load_lds((const __attribute__((address_space(1))) void*)g,
                                   (__attribute__((address_space(3))) void*)l,
                                   16, 0, 0);
}

// ---------------- fp32 -> bf16 convert (vectorized) ----------------
__global__ void cvt_kernel(const float* __restrict__ in, u16* __restrict__ out, int n4) {
  for (int i = blockIdx.x * blockDim.x + threadIdx.x; i < n4; i += gridDim.x * blockDim.x) {
    float4 v = reinterpret_cast<const float4*>(in)[i];
    u16x4 o;
    o[0] = f2bf(v.x); o[1] = f2bf(v.y); o[2] = f2bf(v.z); o[3] = f2bf(v.w);
    reinterpret_cast<u16x4*>(out)[i] = o;
  }
}

// ---------------- weight transpose + convert: W[K][N] -> Wt[N][K] bf16 ----------------
__global__ void tcvt_kernel(const float* __restrict__ W, u16* __restrict__ Wt, int K, int N) {
  int idx = blockIdx.x * blockDim.x + threadIdx.x;
  if (idx >= K * N) return;
  int n = idx / K, k = idx % K;
  Wt[idx] = f2bf(W[k * N + n]);
}

// ---------------- 256x256 8-phase NT GEMM: C[M][N] = A[M][K] * Bt[N][K]^T ----------
// BM=BN=256, BK=64, 8 waves (2M x 4N), double-buffered LDS, T2 XOR-swizzle,
// counted vmcnt, setprio around MFMA clusters. K must be a multiple of 128.
// Stage discipline: a gl_lds may only target a region whose last reads are
// closed by an end-of-phase barrier. A reads span all 4 phases -> A(u+1) is
// staged into the opposite-parity (idle) buffer @p1/p2. B reads are all in
// phase 1 -> B(u+2) staged into same-parity buffer @p3/p4. vmcnt(4) per tile.
template <bool OUT_F32>
__global__ __launch_bounds__(512, 2) void gemm256(const u16* __restrict__ A,
                                                  const u16* __restrict__ Bt,
                                                  void* __restrict__ Cp,
                                                  int M, int N, int K) {
  __shared__ __align__(16) u16 Al[2][16384];
  __shared__ __align__(16) u16 Bl[2][16384];
  const int nbn = N >> 8;
  const int nwg = gridDim.x;
  const int bid0 = blockIdx.x;
  const int cpx = nwg >> 3;  // grid % 8 == 0 for all our shapes
  const int bid = (bid0 & 7) * cpx + (bid0 >> 3);
  const int bm = bid / nbn, bn = bid % nbn;
  const size_t row0 = (size_t)bm << 8, col0 = (size_t)bn << 8;
  const int tid = threadIdx.x, lane = tid & 63;
  const int wv = tid >> 6, wm = wv >> 2, wn = wv & 3;
  const int ro = lane & 15, g4 = lane >> 4;
  const int NT = K >> 6;

  // staging geometry: chunk ci covers (row=ci>>3, colgroup=ci&7) of a 128x64 half-tile.
  // LDS dest is LINEAR; global source colgroup pre-swizzled: gg = g ^ (row&7).
  const int ci0 = tid, ci1 = tid + 512;
  const int r0 = ci0 >> 3, g0 = (ci0 & 7) ^ (r0 & 7);
  const int r1 = ci1 >> 3, g1 = (ci1 & 7) ^ (r1 & 7);

  auto stageA = [&](int half, int kt, u16* L) {
    gl_lds16(A + (row0 + half * 128 + r0) * (size_t)K + kt * 64 + g0 * 8, L + half * 8192 + ci0 * 8);
    gl_lds16(A + (row0 + half * 128 + r1) * (size_t)K + kt * 64 + g1 * 8, L + half * 8192 + ci1 * 8);
  };
  auto stageB = [&](int half, int kt, u16* L) {
    gl_lds16(Bt + (col0 + half * 128 + r0) * (size_t)K + kt * 64 + g0 * 8, L + half * 8192 + ci0 * 8);
    gl_lds16(Bt + (col0 + half * 128 + r1) * (size_t)K + kt * 64 + g1 * 8, L + half * 8192 + ci1 * 8);
  };

  // ds_read offsets (u16 elements), swizzled: phys colgroup = logical ^ (row&7)
  const int aB = (wm * 128 + ro) * 64;
  const int bB = (wn * 64 + ro) * 64;
  const int sw0 = (g4 ^ (ro & 7)) * 8;
  const int sw1 = ((g4 + 4) ^ (ro & 7)) * 8;

  auto ldf = [&](const u16* p) { return *reinterpret_cast<const bf16x8*>(p); };

  f32x4 acc[8][4] = {};

  // prologue: tile 0 fully + B of tile 1. Queue: [A(0)^4, B(0)^4, B(1)^4].
  stageA(0, 0, Al[0]); stageA(1, 0, Al[0]); stageB(0, 0, Bl[0]); stageB(1, 0, Bl[0]);
  stageB(0, 1, Bl[1]); stageB(1, 1, Bl[1]);
  asm volatile("s_waitcnt vmcnt(4)" ::: "memory");  // drain A(0)+B(0); B(1) in flight
  __builtin_amdgcn_s_barrier();

  for (int t = 0; t < NT; t += 2) {
#pragma unroll
    for (int half = 0; half < 2; ++half) {
      const int u = t + half;
      u16* LA = Al[half];
      u16* LB = Bl[half];
      u16* LAn = Al[half ^ 1];
      const bool stA = (u + 1) < NT;
      const bool stB = (u + 2) < NT;
      bf16x8 bfr[4][2], af[2][2];

      // ---- phase 1: all B frags + A m0,m1; stage A half0 (u+1) into idle buffer ----
#pragma unroll
      for (int n = 0; n < 4; ++n) {
        bfr[n][0] = ldf(LB + bB + n * 1024 + sw0);
        bfr[n][1] = ldf(LB + bB + n * 1024 + sw1);
      }
      af[0][0] = ldf(LA + aB + sw0);        af[0][1] = ldf(LA + aB + sw1);
      af[1][0] = ldf(LA + aB + 1024 + sw0); af[1][1] = ldf(LA + aB + 1024 + sw1);
      if (stA) stageA(0, u + 1, LAn);
      __builtin_amdgcn_s_barrier();
      asm volatile("s_waitcnt lgkmcnt(0)" ::: "memory");
      __builtin_amdgcn_sched_barrier(0);
      __builtin_amdgcn_s_setprio(1);
#pragma unroll
      for (int m = 0; m < 2; ++m)
#pragma unroll
        for (int n = 0; n < 4; ++n) {
          acc[m][n] = __builtin_amdgcn_mfma_f32_16x16x32_bf16(af[m][0], bfr[n][0], acc[m][n], 0, 0, 0);
          acc[m][n] = __builtin_amdgcn_mfma_f32_16x16x32_bf16(af[m][1], bfr[n][1], acc[m][n], 0, 0, 0);
        }
      __builtin_amdgcn_s_setprio(0);
      __builtin_amdgcn_s_barrier();

      // ---- phases 2..4: A m=2ph..2ph+1; stage Ah1(u+1) / Bh0(u+2) / Bh1(u+2) ----
#pragma unroll
      for (int ph = 1; ph < 4; ++ph) {
        af[0][0] = ldf(LA + aB + (2 * ph) * 1024 + sw0);
        af[0][1] = ldf(LA + aB + (2 * ph) * 1024 + sw1);
        af[1][0] = ldf(LA + aB + (2 * ph + 1) * 1024 + sw0);
        af[1][1] = ldf(LA + aB + (2 * ph + 1) * 1024 + sw1);
        if (ph == 1) { if (stA) stageA(1, u + 1, LAn); }
        else if (ph == 2) { if (stB) stageB(0, u + 2, LB); }
        else { if (stB) stageB(1, u + 2, LB); }
        __builtin_amdgcn_s_barrier();
        asm volatile("s_waitcnt lgkmcnt(0)" ::: "memory");
        __builtin_amdgcn_sched_barrier(0);
        __builtin_amdgcn_s_setprio(1);
#pragma unroll
        for (int m = 0; m < 2; ++m)
#pragma unroll
          for (int n = 0; n < 4; ++n) {
            acc[2 * ph + m][n] =
                __builtin_amdgcn_mfma_f32_16x16x32_bf16(af[m][0], bfr[n][0], acc[2 * ph + m][n], 0, 0, 0);
            acc[2 * ph + m][n] =
                __builtin_amdgcn_mfma_f32_16x16x32_bf16(af[m][1], bfr[n][1], acc[2 * ph + m][n], 0, 0, 0);
          }
        __builtin_amdgcn_s_setprio(0);
        if (ph == 3) {
          if (stB) asm volatile("s_waitcnt vmcnt(4)" ::: "memory");
          else     asm volatile("s_waitcnt vmcnt(0)" ::: "memory");
        }
        __builtin_amdgcn_s_barrier();
      }
    }
  }

  // epilogue: C write
#pragma unroll
  for (int m = 0; m < 8; ++m)
#pragma unroll
    for (int n = 0; n < 4; ++n)
#pragma unroll
      for (int j = 0; j < 4; ++j) {
        size_t r = row0 + wm * 128 + m * 16 + g4 * 4 + j;
        size_t c = col0 + wn * 64 + n * 16 + ro;
        if (OUT_F32)
          reinterpret_cast<float*>(Cp)[r * N + c] = acc[m][n][j];
        else
          reinterpret_cast<u16*>(Cp)[r * N + c] = f2bf(acc[m][n][j]);
      }
}

// ---------------- window attention ----------------
// grid: b*512 + w*8 + h  (2048 blocks), 512 threads (8 waves, 32 q-rows each)
// Two 16-row q-tiles per wave processed SEQUENTIALLY (static indexing, no spill).
__global__ __launch_bounds__(512, 2) void attn_kernel(const u16* __restrict__ qp,
                                                      const u16* __restrict__ kvp,
                                                      u16* __restrict__ o) {
  __shared__ __align__(16) u16 Kl[256 * 72];       // K tile, padded rows
  __shared__ __align__(16) u16 Vt[64 * 264];       // V transposed, padded rows
  __shared__ __align__(16) u16 Pl[8 * 16 * 264];   // per-wave P row-tile
  const int bid = blockIdx.x;
  const int h = bid & 7, w = (bid >> 3) & 63, b = bid >> 9;
  const int w1 = w >> 3, w2 = w & 7;
  const int tid = threadIdx.x, lane = tid & 63, wv = tid >> 6;

  auto lrow = [&](int t) { return (w1 * 16 + (t >> 4)) * 128 + w2 * 16 + (t & 15); };

  {  // stage K rows and V transposed
    const int t = tid >> 1, half = tid & 1;
    const size_t base = ((size_t)(b * LL + lrow(t))) * 1024 + h * 64 + half * 32;
    const u16* kr = kvp + base;
    const u16* vr = kvp + base + 512;
#pragma unroll
    for (int c = 0; c < 4; ++c) {
      u16x8 kx = *reinterpret_cast<const u16x8*>(kr + c * 8);
      *reinterpret_cast<u16x8*>(&Kl[t * 72 + half * 32 + c * 8]) = kx;
    }
#pragma unroll
    for (int c = 0; c < 4; ++c) {
      u16x8 vx = *reinterpret_cast<const u16x8*>(vr + c * 8);
#pragma unroll
      for (int e = 0; e < 8; ++e) Vt[(half * 32 + c * 8 + e) * 264 + t] = vx[e];
    }
  }
  __syncthreads();

  const int ro = lane & 15;       // low nibble
  const int g4 = lane >> 4;       // lane group 0..3
  const float scale = 0.125f;     // hd^-0.5, hd=64
  const int pbase = wv * 16 * 264;

#pragma unroll
  for (int rt = 0; rt < 2; ++rt) {
    // Q fragments for this 16-row tile, direct from global
    const int tq = 32 * wv + 16 * rt + ro;
    const size_t qbase = ((size_t)(b * LL + lrow(tq))) * 512 + h * 64 + g4 * 8;
    const bf16x8 qf0 = *reinterpret_cast<const bf16x8*>(qp + qbase);
    const bf16x8 qf1 = *reinterpret_cast<const bf16x8*>(qp + qbase + 32);

    // S = Q K^T : 16 q-rows x 256 keys
    f32x4 sa[16] = {};
#pragma unroll
    for (int ct = 0; ct < 16; ++ct) {
      bf16x8 kf0 = *reinterpret_cast<const bf16x8*>(&Kl[(16 * ct + ro) * 72 + g4 * 8]);
      bf16x8 kf1 = *reinterpret_cast<const bf16x8*>(&Kl[(16 * ct + ro) * 72 + 32 + g4 * 8]);
      sa[ct] = __builtin_amdgcn_mfma_f32_16x16x32_bf16(qf0, kf0, sa[ct], 0, 0, 0);
      sa[ct] = __builtin_amdgcn_mfma_f32_16x16x32_bf16(qf1, kf1, sa[ct], 0, 0, 0);
    }

    // softmax per q-row (row = g4*4 + j, key = 16*ct + ro)
#pragma unroll
    for (int j = 0; j < 4; ++j) {
      float m = -1e30f;
#pragma unroll
      for (int ct = 0; ct < 16; ++ct) m = fmaxf(m, sa[ct][j]);
      m = fmaxf(m, __shfl_xor(m, 1));
      m = fmaxf(m, __shfl_xor(m, 2));
      m = fmaxf(m, __shfl_xor(m, 4));
      m = fmaxf(m, __shfl_xor(m, 8));
      m *= scale;
      float s = 0.f;
#pragma unroll
      for (int ct = 0; ct < 16; ++ct) {
        float p = __expf(sa[ct][j] * scale - m);
        sa[ct][j] = p;
        s += p;
      }
      s += __shfl_xor(s, 1);
      s += __shfl_xor(s, 2);
      s += __shfl_xor(s, 4);
      s += __shfl_xor(s, 8);
      float inv = 1.f / s;
#pragma unroll
      for (int ct = 0; ct < 16; ++ct)
        Pl[pbase + (g4 * 4 + j) * 264 + 16 * ct + ro] = f2bf(sa[ct][j] * inv);
    }

    // O = P V  (per-wave LDS region; in-wave DS ordering suffices, no barrier)
    f32x4 oacc[4] = {};
#pragma unroll
    for (int ks = 0; ks < 8; ++ks) {
      bf16x8 pf = *reinterpret_cast<const bf16x8*>(&Pl[pbase + ro * 264 + ks * 32 + g4 * 8]);
#pragma unroll
      for (int cd = 0; cd < 4; ++cd) {
        bf16x8 vf = *reinterpret_cast<const bf16x8*>(&Vt[(16 * cd + ro) * 264 + ks * 32 + g4 * 8]);
        oacc[cd] = __builtin_amdgcn_mfma_f32_16x16x32_bf16(pf, vf, oacc[cd], 0, 0, 0);
      }
    }

    // write out this 16-row tile
#pragma unroll
    for (int cd = 0; cd < 4; ++cd)
#pragma unroll
      for (int j = 0; j < 4; ++j) {
        int t = 32 * wv + 16 * rt + g4 * 4 + j;
        int d = 16 * cd + ro;
        o[((size_t)(b * LL + lrow(t))) * 512 + h * 64 + d] = f2bf(oacc[cd][j]);
      }
  }
}

// ---------------- launch ----------------
extern "C" void kernel_launch(void* const* d_in, const int* in_sizes, int n_in,
                              void* d_out, int out_size, void* d_ws, size_t ws_size,
                              hipStream_t stream) {
  const float* q = (const float*)d_in[0];
  const float* kv = (const float*)d_in[1];
  const float* Wq = (const float*)d_in[2];
  const float* Wkv = (const float*)d_in[3];
  const float* Wfc = (const float*)d_in[4];
  float* out = (float*)d_out;
  char* ws = (char*)d_ws;

  // workspace layout (bytes)
  u16* q_bf  = (u16*)(ws + 0);            // 67108864  (also reused as o_buf)
  u16* kv_bf = (u16*)(ws + 67108864);     // 67108864
  u16* qp    = (u16*)(ws + 134217728);    // 67108864
  u16* kvp   = (u16*)(ws + 201326592);    // 134217728
  u16* Wq_t  = (u16*)(ws + 335544320);    // 524288
  u16* Wkv_t = (u16*)(ws + 336068608);    // 1048576
  u16* Wfc_t = (u16*)(ws + 337117184);    // 524288
  u16* o_buf = q_bf;                      // q_bf dead after GEMM1

  const int n4 = MM * CC / 4;  // 8388608
  cvt_kernel<<<2048, 256, 0, stream>>>(q, q_bf, n4);
  cvt_kernel<<<2048, 256, 0, stream>>>(kv, kv_bf, n4);
  tcvt_kernel<<<(CC * CC + 255) / 256, 256, 0, stream>>>(Wq, Wq_t, CC, CC);
  tcvt_kernel<<<(CC * 2 * CC + 255) / 256, 256, 0, stream>>>(Wkv, Wkv_t, CC, 2 * CC);
  tcvt_kernel<<<(CC * CC + 255) / 256, 256, 0, stream>>>(Wfc, Wfc_t, CC, CC);

  gemm256<false><<<(MM / 256) * (CC / 256), 512, 0, stream>>>(q_bf, Wq_t, qp, MM, CC, CC);
  gemm256<false><<<(MM / 256) * (2 * CC / 256), 512, 0, stream>>>(kv_bf, Wkv_t, kvp, MM, 2 * CC, CC);

  attn_kernel<<<BB * 64 * 8, 512, 0, stream>>>(qp, kvp, o_buf);

  gemm256<true><<<(MM / 256) * (CC / 256), 512, 0, stream>>>(o_buf, Wfc_t, out, MM, CC, CC);
}